// Round 3
// baseline (1119.401 us; speedup 1.0000x reference)
//
#include <hip/hip_runtime.h>
#include <math.h>

// Shapes (hardcoded from reference): B=8,T=12,N=1000,D=256,H=8,R=32,HD=32,E=1024
#define MT 96000   // B*T*N tokens
#define DD 256
#define EE 1024
#define NBT 96     // B*T
#define NSEQ 1000

typedef __attribute__((ext_vector_type(8))) short bf16x8;
typedef __attribute__((ext_vector_type(4))) short bf16x4;
typedef __attribute__((ext_vector_type(4))) float f32x4;

__device__ __forceinline__ short f2b(float f) {
  union { float f; unsigned u; } v; v.f = f;
  unsigned r = (v.u + 0x7FFFu + ((v.u >> 16) & 1u)) >> 16;
  return (short)r;
}
__device__ __forceinline__ float b2f(short s) {
  union { unsigned u; float f; } v; v.u = ((unsigned)(unsigned short)s) << 16;
  return v.f;
}
__device__ __forceinline__ float sigf(float x) { return 1.f / (1.f + __expf(-x)); }
__device__ __forceinline__ f32x4 mfma16(bf16x8 a, bf16x8 b, f32x4 c) {
  return __builtin_amdgcn_mfma_f32_16x16x32_bf16(a, b, c, 0, 0, 0);
}
// XOR-swizzled LDS octet offset: row stride = rowlen shorts (multiple of 64),
// octet o (8 shorts) placed at o ^ (row&7). Bank-equivalent to +8 pad, no pad.
__device__ __forceinline__ int swz(int row, int o, int rowlen) {
  return row * rowlen + (((o) ^ (row & 7)) << 3);
}

// ---------------------------------------------------------------------------
// K0: weight prep. Transposed bf16 weights ([out][in]); coalesced READS,
// scattered writes (L2 absorbs). Plus fused Wqk = (Wq . key)/sqrt(HD), bqk.
// ---------------------------------------------------------------------------
__global__ __launch_bounds__(256) void k_prep(
    const float* __restrict__ Wq, const float* __restrict__ bq,
    const float* __restrict__ key, const float* __restrict__ Wv,
    const float* __restrict__ W1, const float* __restrict__ W2,
    const float* __restrict__ W3,
    short* __restrict__ W1t, short* __restrict__ W2t, short* __restrict__ W3t,
    short* __restrict__ Wvt, short* __restrict__ Wqkt, float* __restrict__ bqk)
{
  int i = blockIdx.x * 256 + threadIdx.x;   // 0 .. 262143
  { int c = i >> 10, e = i & 1023;          // W1/W2 [c][e] -> [e][c]
    W1t[e * 256 + c] = f2b(W1[i]);
    W2t[e * 256 + c] = f2b(W2[i]); }
  { int e = i >> 8, n = i & 255;            // W3 [e][n] -> [n][e]
    W3t[n * 1024 + e] = f2b(W3[i]); }
  if (i < 65536) {
    { int c = i >> 8, n = i & 255;          // Wv [c][n] -> [n][c]
      Wvt[n * 256 + c] = f2b(Wv[i]); }
    int n = i >> 8, c = i & 255;            // Wqk (n uniform per block)
    int h = n >> 5, r = n & 31;
    float acc = 0.f;
    for (int d = 0; d < 32; ++d)
      acc += Wq[c * DD + h * 32 + d] * key[(r * 8 + h) * 32 + d];
    Wqkt[i] = f2b(acc * 0.17677669529663687f);  // 1/sqrt(32)
  }
  if (i < 256) {
    int h = i >> 5, r = i & 31;
    float acc = 0.f;
    for (int d = 0; d < 32; ++d)
      acc += bq[h * 32 + d] * key[(r * 8 + h) * 32 + d];
    bqk[i] = acc * 0.17677669529663687f;
  }
}

// ---------------------------------------------------------------------------
// K1: fused RMSNorm: x1 = rms(x)*w1 ; z1 = rms(sg*x1 + sd*z)*w2. bf16 out.
// One wave per token. NT loads: x,z are single-use.
// ---------------------------------------------------------------------------
__global__ __launch_bounds__(256) void k_norm(
    const float* __restrict__ x, const float* __restrict__ z,
    const float* __restrict__ nw1, const float* __restrict__ nw2,
    const float* __restrict__ gamma, const float* __restrict__ delta,
    short* __restrict__ x1bp, short* __restrict__ z1bp)
{
  int tok = blockIdx.x * 4 + (threadIdx.x >> 6);
  int lane = threadIdx.x & 63;
  size_t rbase = (size_t)tok * DD;
  f32x4 xv = __builtin_nontemporal_load((const f32x4*)(x + rbase) + lane);
  float ss = xv.x*xv.x + xv.y*xv.y + xv.z*xv.z + xv.w*xv.w;
  #pragma unroll
  for (int mm = 1; mm < 64; mm <<= 1) ss += __shfl_xor(ss, mm);
  float inv = rsqrtf(ss * 0.00390625f + 1e-6f);
  f32x4 wv = ((const f32x4*)nw1)[lane];
  float xa = xv.x * inv * wv.x, xb = xv.y * inv * wv.y,
        xc = xv.z * inv * wv.z, xd = xv.w * inv * wv.w;
  bf16x4 xo = { f2b(xa), f2b(xb), f2b(xc), f2b(xd) };
  ((bf16x4*)(x1bp + rbase))[lane] = xo;
  float sg = sigf(gamma[0]), sd = sigf(delta[0]);
  f32x4 zv = __builtin_nontemporal_load((const f32x4*)(z + rbase) + lane);
  float t0 = sg*xa + sd*zv.x, t1 = sg*xb + sd*zv.y,
        t2 = sg*xc + sd*zv.z, t3 = sg*xd + sd*zv.w;
  float s2 = t0*t0 + t1*t1 + t2*t2 + t3*t3;
  #pragma unroll
  for (int mm = 1; mm < 64; mm <<= 1) s2 += __shfl_xor(s2, mm);
  float inv2 = rsqrtf(s2 * 0.00390625f + 1e-6f);
  f32x4 w2v = ((const f32x4*)nw2)[lane];
  bf16x4 zo = { f2b(t0*inv2*w2v.x), f2b(t1*inv2*w2v.y),
                f2b(t2*inv2*w2v.z), f2b(t3*inv2*w2v.w) };
  ((bf16x4*)(z1bp + rbase))[lane] = zo;
}

// ---------------------------------------------------------------------------
// K2/K3: C_bf16[MT,256] = A_bf16[MT,256] @ Bt^T + bias. Bt is [n][k].
// Block: 64 rows; A staged ONCE (swizzled), loop 4 col-tiles restaging Bs.
// ---------------------------------------------------------------------------
__global__ __launch_bounds__(256) void k_gemm256(
    const short* __restrict__ A, const short* __restrict__ Bt,
    const float* __restrict__ bias, short* __restrict__ C)
{
  __shared__ __align__(16) short As[64 * 256];
  __shared__ __align__(16) short Bs[64 * 256];
  int row0 = blockIdx.x * 64;
  int tid = threadIdx.x, lane = tid & 63, w = tid >> 6;
  int l15 = lane & 15, q = lane >> 4;
  int mh = (w & 1) * 32, nh = (w >> 1) * 32;
  #pragma unroll
  for (int it = 0; it < 8; ++it) {
    int idx = it * 256 + tid, rw = idx >> 5, o = idx & 31;
    *(bf16x8*)&As[swz(rw, o, 256)] = *(const bf16x8*)&A[(row0 + rw) * 256 + o * 8];
  }
  for (int ct = 0; ct < 4; ++ct) {
    int col0 = ct * 64;
    #pragma unroll
    for (int it = 0; it < 8; ++it) {
      int idx = it * 256 + tid, rw = idx >> 5, o = idx & 31;
      *(bf16x8*)&Bs[swz(rw, o, 256)] = *(const bf16x8*)&Bt[(col0 + rw) * 256 + o * 8];
    }
    __syncthreads();
    f32x4 acc[2][2] = {};
    #pragma unroll
    for (int kk = 0; kk < 8; ++kk) {
      bf16x8 af[2], bfr[2];
      #pragma unroll
      for (int t = 0; t < 2; ++t) {
        int m = mh + t * 16 + l15;
        af[t] = *(const bf16x8*)&As[swz(m, kk * 4 + q, 256)];
        int n = nh + t * 16 + l15;
        bfr[t] = *(const bf16x8*)&Bs[swz(n, kk * 4 + q, 256)];
      }
      #pragma unroll
      for (int tm = 0; tm < 2; ++tm)
        #pragma unroll
        for (int tn = 0; tn < 2; ++tn)
          acc[tm][tn] = mfma16(af[tm], bfr[tn], acc[tm][tn]);
    }
    #pragma unroll
    for (int tm = 0; tm < 2; ++tm)
      #pragma unroll
      for (int tn = 0; tn < 2; ++tn) {
        int n = col0 + nh + tn * 16 + l15;
        float bv = bias[n];
        #pragma unroll
        for (int r = 0; r < 4; ++r) {
          int m = row0 + mh + tm * 16 + q * 4 + r;
          C[m * 256 + n] = f2b(acc[tm][tn][r] + bv);
        }
      }
    __syncthreads();
  }
}

// ---------------------------------------------------------------------------
// K4: fused SwiGLU FFN. 64 rows x 256 cols per block; E chunked by 128 via
// bf16 LDS round-trip. Swizzled As (32KB) + Hs (16KB) = 48KB -> 3 blocks/CU.
// ---------------------------------------------------------------------------
__global__ __launch_bounds__(256) void k_ffn(
    const short* __restrict__ x1bp,
    const short* __restrict__ W1t, const short* __restrict__ W2t,
    const short* __restrict__ W3t,
    const float* __restrict__ b1, const float* __restrict__ b2,
    const float* __restrict__ b3, const float* __restrict__ alpha,
    float* __restrict__ out)
{
  __shared__ __align__(16) short As[64 * 256];
  __shared__ __align__(16) short Hs[64 * 128];
  int row0 = blockIdx.x * 64;
  int tid = threadIdx.x, lane = tid & 63, w = tid >> 6;
  int l15 = lane & 15, q = lane >> 4;
  #pragma unroll
  for (int it = 0; it < 8; ++it) {
    int idx = it * 256 + tid, rw = idx >> 5, o = idx & 31;
    *(bf16x8*)&As[swz(rw, o, 256)] = *(const bf16x8*)&x1bp[(row0 + rw) * 256 + o * 8];
  }
  __syncthreads();
  f32x4 oacc[4][4] = {};
  for (int ec = 0; ec < 8; ++ec) {
    int e0 = ec * 128;
    f32x4 h1[4][2] = {}, h2[4][2] = {};
    #pragma unroll
    for (int kk = 0; kk < 8; ++kk) {
      bf16x8 af[4];
      #pragma unroll
      for (int tm = 0; tm < 4; ++tm) {
        int m = tm * 16 + l15;
        af[tm] = *(const bf16x8*)&As[swz(m, kk * 4 + q, 256)];
      }
      #pragma unroll
      for (int tn = 0; tn < 2; ++tn) {
        int e = e0 + w * 32 + tn * 16 + l15;
        bf16x8 w1f = *(const bf16x8*)&W1t[e * 256 + kk * 32 + q * 8];
        bf16x8 w2f = *(const bf16x8*)&W2t[e * 256 + kk * 32 + q * 8];
        #pragma unroll
        for (int tm = 0; tm < 4; ++tm) {
          h1[tm][tn] = mfma16(af[tm], w1f, h1[tm][tn]);
          h2[tm][tn] = mfma16(af[tm], w2f, h2[tm][tn]);
        }
      }
    }
    #pragma unroll
    for (int tn = 0; tn < 2; ++tn) {
      int e = e0 + w * 32 + tn * 16 + l15;
      float c1 = b1[e], c2 = b2[e];
      int eloc = w * 32 + tn * 16 + l15;
      #pragma unroll
      for (int tm = 0; tm < 4; ++tm)
        #pragma unroll
        for (int r = 0; r < 4; ++r) {
          float v1 = h1[tm][tn][r] + c1;
          float v2 = h2[tm][tn][r] + c2;
          float hv = v1 * sigf(v1) * v2;  // silu(v1) * v2
          int m = tm * 16 + q * 4 + r;
          Hs[swz(m, eloc >> 3, 128) + (eloc & 7)] = f2b(hv);
        }
    }
    __syncthreads();
    #pragma unroll
    for (int kk = 0; kk < 4; ++kk) {
      bf16x8 hf[4];
      #pragma unroll
      for (int tm = 0; tm < 4; ++tm) {
        int m = tm * 16 + l15;
        hf[tm] = *(const bf16x8*)&Hs[swz(m, kk * 4 + q, 128)];
      }
      #pragma unroll
      for (int tn = 0; tn < 4; ++tn) {
        int n = w * 64 + tn * 16 + l15;
        bf16x8 w3f = *(const bf16x8*)&W3t[n * 1024 + e0 + kk * 32 + q * 8];
        #pragma unroll
        for (int tm = 0; tm < 4; ++tm)
          oacc[tm][tn] = mfma16(hf[tm], w3f, oacc[tm][tn]);
      }
    }
    __syncthreads();
  }
  float sa = sigf(alpha[0]);
  #pragma unroll
  for (int tn = 0; tn < 4; ++tn) {
    int n = w * 64 + tn * 16 + l15;
    float bb = b3[n];
    #pragma unroll
    for (int tm = 0; tm < 4; ++tm)
      #pragma unroll
      for (int r = 0; r < 4; ++r) {
        int m = row0 + tm * 16 + q * 4 + r;
        out[m * 256 + n] = sa * (oacc[tm][tn][r] + bb);
      }
  }
}

// ---------------------------------------------------------------------------
// K5: attention pass 1, barrier-free main loop. Block per (bt,h).
// Thread (r = tid&31, nl = tid>>5): row-softmax over r via shfl (32-lane),
// xv broadcast via shfl, accd[32] per-thread partial of v1[r][*].
// ---------------------------------------------------------------------------
__global__ __launch_bounds__(256) void k_attn1(
    const short* __restrict__ attnb, const short* __restrict__ xvb,
    float* __restrict__ v1buf, float* __restrict__ colmax, float* __restrict__ colsum)
{
  __shared__ float red[4][32][33];
  __shared__ float mred[4][32], sred[4][32];
  int gid = blockIdx.x, bt = gid >> 3, h = gid & 7;
  int tid = threadIdx.x, r = tid & 31, nl = tid >> 5;
  int hi = tid & 32;
  int base = bt * NSEQ;
  float accd[32];
  #pragma unroll
  for (int d = 0; d < 32; ++d) accd[d] = 0.f;
  float mrun = -1e30f, srun = 0.f;
  for (int it = 0; it < 125; ++it) {
    int tok = base + it * 8 + nl;
    float a = b2f(attnb[tok * 256 + h * 32 + r]);
    float xvv = b2f(xvb[tok * 256 + h * 32 + r]);
    float rmax = a;
    #pragma unroll
    for (int mm = 16; mm > 0; mm >>= 1) rmax = fmaxf(rmax, __shfl_xor(rmax, mm));
    float ea = __expf(a - rmax);
    float rsum = ea;
    #pragma unroll
    for (int mm = 16; mm > 0; mm >>= 1) rsum += __shfl_xor(rsum, mm);
    float p1 = ea / rsum;
    float nm = fmaxf(mrun, a);
    srun = srun * __expf(mrun - nm) + __expf(a - nm);
    mrun = nm;
    #pragma unroll
    for (int d = 0; d < 32; ++d)
      accd[d] += p1 * __shfl(xvv, hi + d);
  }
  // merge nl pairs within wave (lanes tid and tid^32 share r)
  #pragma unroll
  for (int d = 0; d < 32; ++d) accd[d] += __shfl_xor(accd[d], 32);
  float mo = __shfl_xor(mrun, 32), so = __shfl_xor(srun, 32);
  float mm2 = fmaxf(mrun, mo);
  float ss2 = srun * __expf(mrun - mm2) + so * __expf(mo - mm2);
  int wv = tid >> 6;
  if (hi == 0) {
    #pragma unroll
    for (int d = 0; d < 32; ++d) red[wv][r][d] = accd[d];
    mred[wv][r] = mm2; sred[wv][r] = ss2;
  }
  __syncthreads();
  #pragma unroll
  for (int j = 0; j < 4; ++j) {
    int flat = j * 256 + tid, rr = flat >> 5, dd = flat & 31;
    v1buf[gid * 1024 + flat] =
        red[0][rr][dd] + red[1][rr][dd] + red[2][rr][dd] + red[3][rr][dd];
  }
  if (tid < 32) {
    float M = fmaxf(fmaxf(mred[0][tid], mred[1][tid]), fmaxf(mred[2][tid], mred[3][tid]));
    float S = 0.f;
    #pragma unroll
    for (int j = 0; j < 4; ++j) S += sred[j][tid] * __expf(mred[j][tid] - M);
    colmax[gid * 32 + tid] = M;
    colsum[gid * 32 + tid] = S;
  }
}

// ---------------------------------------------------------------------------
// K6: attention pass 2 + final blend, barrier-free main loop.
// Block per (bt, chunk of 125 tokens); thread = column c = h*32+d.
// p2 broadcast via shfl; v1 rows from LDS (conflict-free).
// ---------------------------------------------------------------------------
__global__ __launch_bounds__(256) void k_attn2(
    const short* __restrict__ attnb, const short* __restrict__ xvb,
    const float* __restrict__ v1buf, const float* __restrict__ colmax,
    const float* __restrict__ colsum, const float* __restrict__ mha_alpha,
    const float* __restrict__ mha_beta, const float* __restrict__ beta,
    float* __restrict__ out)
{
  __shared__ float v1s[8192];
  __shared__ float cms[256], rcs[256];
  __shared__ float sas[8], sbs[8];
  int bt = blockIdx.x, chunk = blockIdx.y;
  int tid = threadIdx.x;
  #pragma unroll
  for (int j = 0; j < 32; ++j) v1s[j * 256 + tid] = v1buf[bt * 8192 + j * 256 + tid];
  cms[tid] = colmax[bt * 256 + tid];
  rcs[tid] = 1.f / colsum[bt * 256 + tid];
  if (tid < 8) { sas[tid] = sigf(mha_alpha[tid]); sbs[tid] = sigf(mha_beta[tid]); }
  __syncthreads();
  float sbeta = sigf(beta[0]);
  int h = tid >> 5, d = tid & 31, hi = tid & 32;
  float cmv = cms[tid], rcv = rcs[tid];
  float sav = sas[h] * sbeta, sbv = sbs[h] * sbeta;
  const float* v1p = &v1s[h * 1024 + d];
  for (int tl = 0; tl < 125; ++tl) {
    int tok = bt * NSEQ + chunk * 125 + tl;
    float a = b2f(attnb[tok * 256 + tid]);
    float p2 = __expf(a - cmv) * rcv;
    float xvv = b2f(xvb[tok * 256 + tid]);
    float v2 = 0.f;
    #pragma unroll
    for (int rr = 0; rr < 32; ++rr)
      v2 += __shfl(p2, hi + rr) * v1p[rr * 32];
    float res = out[tok * 256 + tid] + sav * xvv + sbv * v2;
    __builtin_nontemporal_store(res, &out[tok * 256 + tid]);
  }
}

// ---------------------------------------------------------------------------
extern "C" void kernel_launch(void* const* d_in, const int* in_sizes, int n_in,
                              void* d_out, int out_size, void* d_ws, size_t ws_size,
                              hipStream_t stream) {
  const float* x        = (const float*)d_in[0];
  const float* z        = (const float*)d_in[1];
  const float* norm1_w  = (const float*)d_in[2];
  const float* norm2_w  = (const float*)d_in[3];
  const float* alpha    = (const float*)d_in[4];
  const float* beta     = (const float*)d_in[5];
  const float* gamma    = (const float*)d_in[6];
  const float* delta    = (const float*)d_in[7];
  const float* Wq       = (const float*)d_in[8];
  const float* bq       = (const float*)d_in[9];
  const float* key      = (const float*)d_in[10];
  const float* Wv       = (const float*)d_in[11];
  const float* bv       = (const float*)d_in[12];
  const float* mha_a    = (const float*)d_in[13];
  const float* mha_b    = (const float*)d_in[14];
  const float* W1       = (const float*)d_in[15];
  const float* b1       = (const float*)d_in[16];
  const float* W2       = (const float*)d_in[17];
  const float* b2       = (const float*)d_in[18];
  const float* W3       = (const float*)d_in[19];
  const float* b3       = (const float*)d_in[20];
  float* out = (float*)d_out;
  char* ws = (char*)d_ws;

  short* x1b   = (short*)(ws);
  short* z1b   = (short*)(ws + 49152000);
  short* xvb   = (short*)(ws + 98304000);
  short* attnb = (short*)(ws + 147456000);
  short* W1t   = (short*)(ws + 196608000);
  short* W2t   = (short*)(ws + 197132288);
  short* W3t   = (short*)(ws + 197656576);
  short* Wvt   = (short*)(ws + 198180864);
  short* Wqkt  = (short*)(ws + 198311936);
  float* bqk   = (float*)(ws + 198443008);
  float* v1buf = (float*)(ws + 198444032);
  float* colmax= (float*)(ws + 201589760);
  float* colsum= (float*)(ws + 201688064);

  hipLaunchKernelGGL(k_prep, dim3(1024), dim3(256), 0, stream,
                     Wq, bq, key, Wv, W1, W2, W3, W1t, W2t, W3t, Wvt, Wqkt, bqk);
  hipLaunchKernelGGL(k_norm, dim3(MT / 4), dim3(256), 0, stream,
                     x, z, norm1_w, norm2_w, gamma, delta, x1b, z1b);
  hipLaunchKernelGGL(k_gemm256, dim3(MT / 64), dim3(256), 0, stream,
                     z1b, Wqkt, bqk, attnb);
  hipLaunchKernelGGL(k_gemm256, dim3(MT / 64), dim3(256), 0, stream,
                     x1b, Wvt, bv, xvb);
  hipLaunchKernelGGL(k_ffn, dim3(MT / 64), dim3(256), 0, stream,
                     x1b, W1t, W2t, W3t, b1, b2, b3, alpha, out);
  hipLaunchKernelGGL(k_attn1, dim3(NBT * 8), dim3(256), 0, stream,
                     attnb, xvb, v1buf, colmax, colsum);
  hipLaunchKernelGGL(k_attn2, dim3(NBT, 8), dim3(256), 0, stream,
                     attnb, xvb, v1buf, colmax, colsum, mha_a, mha_b, beta, out);
}